// Round 14
// baseline (615.884 us; speedup 1.0000x reference)
//
#include <hip/hip_runtime.h>
#include <math.h>

#define NB 4
#define NPI 12000
#define NM 32
#define NPTS (NB*NPI*NM)      // 1536000
#define NPIL (NB*NPI)         // 48000

// k_moments config
#define K1_BLOCKS 1500
#define K1_STRIDE (K1_BLOCKS*256)   // 384000
#define K1_ITERS 4                  // NPTS / K1_STRIDE
#define NMOM 54                     // 9 Sf + 45 Sff

// heavy-kernel config: 128 points (4 pillars) per batch, all-32-slots uniform
#define CHUNK 128
#define NBATCH (NPTS/CHUNK)   // 12000
#define SB 512
#define LDB 72                // W2T bf16 row stride: 144B (16B-aligned rows)

typedef __attribute__((ext_vector_type(8))) short bfrag;     // 8 bf16 = 4 VGPRs
typedef __attribute__((ext_vector_type(16))) float f32x16;   // MFMA 32x32 acc

// ---------------------------------------------------------------- helpers

__device__ __forceinline__ void make_f(float4 v, int4 cc, int np, int m, float zc, float f[9]) {
  const float cx = ((float)cc.w + 0.5f) * 0.16f + 0.0f;
  const float cy = ((float)cc.z + 0.5f) * 0.16f - 39.68f;
  f[0] = v.x; f[1] = v.y; f[2] = v.z; f[3] = v.w;
  f[4] = v.x - cx; f[5] = v.y - cy; f[6] = cx; f[7] = cy; f[8] = zc;
  const float msk = (m < np) ? 1.0f : 0.0f;
#pragma unroll
  for (int i = 0; i < 9; ++i) f[i] *= msk;
}

// ------------------------------------------------- K1: f-moments

__global__ __launch_bounds__(256) void k_moments(
    const float4* __restrict__ vox, const int4* __restrict__ coords,
    const int* __restrict__ npnts, float* __restrict__ P1) {
  const int t = blockIdx.x * 256 + threadIdx.x;
  float acc[NMOM];
#pragma unroll
  for (int v = 0; v < NMOM; ++v) acc[v] = 0.0f;

#pragma unroll
  for (int j = 0; j < K1_ITERS; ++j) {
    const int pt = t + j * K1_STRIDE;
    const int pil = pt >> 5;
    const int m = pt & 31;
    const float4 v = vox[pt];
    const int4 cc = coords[pil];
    const int np = npnts[pil];
    float z = v.z;
#pragma unroll
    for (int s = 1; s < 32; s <<= 1) z += __shfl_xor(z, s, 32);
    const float zc = z * (1.0f / 32.0f);
    float f[9];
    make_f(v, cc, np, m, zc, f);
    int vi = 0;
#pragma unroll
    for (int i = 0; i < 9; ++i) acc[vi++] += f[i];
#pragma unroll
    for (int i = 0; i < 9; ++i)
#pragma unroll
      for (int jj = i; jj < 9; ++jj) acc[vi++] += f[i] * f[jj];
  }

#pragma unroll
  for (int v = 0; v < NMOM; ++v) {
    float x = acc[v];
#pragma unroll
    for (int s = 1; s < 64; s <<= 1) x += __shfl_xor(x, s, 64);
    acc[v] = x;
  }
  __shared__ float red[4][NMOM];
  const int wave = threadIdx.x >> 6, lane = threadIdx.x & 63;
  if (lane == 0) {
#pragma unroll
    for (int v = 0; v < NMOM; ++v) red[wave][v] = acc[v];
  }
  __syncthreads();
  if (threadIdx.x < NMOM) {
    float s = red[0][threadIdx.x] + red[1][threadIdx.x] + red[2][threadIdx.x] + red[3][threadIdx.x];
    P1[threadIdx.x * K1_BLOCKS + blockIdx.x] = s;
  }
}

// ------------------------------------------------- generic row reduce (f32 -> f64)

__global__ __launch_bounds__(256) void k_rowreduce(
    const float* __restrict__ src, double* __restrict__ dst, int ncols) {
  const int row = blockIdx.x;
  const float* p = src + row * ncols;
  double sd = 0.0;
  for (int i = threadIdx.x; i < ncols; i += 256) sd += (double)p[i];
#pragma unroll
  for (int s = 1; s < 64; s <<= 1) sd += __shfl_xor(sd, s, 64);
  __shared__ double rd[4];
  const int wave = threadIdx.x >> 6, lane = threadIdx.x & 63;
  if (lane == 0) rd[wave] = sd;
  __syncthreads();
  if (threadIdx.x == 0) dst[row] = rd[0] + rd[1] + rd[2] + rd[3];
}

// ------------------------------------------------- finalize layer-1 BN params

__global__ void k_fin1(const double* __restrict__ T1, const float* __restrict__ W1,
                       const float* __restrict__ g1, const float* __restrict__ b1,
                       float* __restrict__ params) {
  const int c = threadIdx.x;  // 64
  double w[9];
#pragma unroll
  for (int i = 0; i < 9; ++i) w[i] = (double)W1[i * 64 + c];
  double mean = 0.0;
#pragma unroll
  for (int i = 0; i < 9; ++i) mean += w[i] * T1[i];
  mean /= (double)NPTS;
  double e2 = 0.0;
  int v = 9;
#pragma unroll
  for (int i = 0; i < 9; ++i)
#pragma unroll
    for (int j = i; j < 9; ++j) {
      const double t = T1[v++] * w[i] * w[j];
      e2 += (i == j) ? t : 2.0 * t;
    }
  e2 /= (double)NPTS;
  const double var = e2 - mean * mean;
  const double a = (double)g1[c] / sqrt(var + 0.001);
  params[c] = (float)a;
  params[64 + c] = (float)((double)b1[c] - mean * a);
}

// ------------------------------------------------- K3: layer-2 via MFMA
// Round-13 structure (MFMA phase B, split-bf16, uniform all-32-slots, no
// barriers in main loop). Round 14: fit 3 blocks/CU & 3 waves/SIMD --
// (a) h1 arrays [128][64] + XOR swizzle (idx ^= (row&7)<<3 in u16 units;
//     conflicts stay ~4-way, all accesses stay 8B/16B aligned since kk, c0
//     round to the XOR granularity);
// (b) end-of-kernel redS/redQ aliased onto h1hi (barrier-separated);
// (c) launch_bounds(256,3) caps VGPR at 170 (natural was 196).
// LDS: 2304+512+16384+16384+9216+9216 = 54016 <= 54613 (3 blocks/CU).

__global__ __launch_bounds__(256, 3) void k_stats2(
    const float4* __restrict__ vox, const int4* __restrict__ coords,
    const int* __restrict__ npnts, const float* __restrict__ W1,
    const float* __restrict__ W2, const float* __restrict__ g2,
    const float* __restrict__ params, float* __restrict__ P2,
    float* __restrict__ Y2SEL) {
  __shared__ __align__(16) float W1t[9 * 64];
  __shared__ __align__(16) float a1s[64], b1s[64];
  __shared__ __align__(16) unsigned short h1hi[128][64];    // 16384 B, swizzled
  __shared__ __align__(16) unsigned short h1lo[128][64];    // 16384 B, swizzled
  __shared__ __align__(16) unsigned short W2Thi[64][LDB];   //  9216 B
  __shared__ __align__(16) unsigned short W2Tlo[64][LDB];   //  9216 B

  const int t = threadIdx.x;
  for (int i = t; i < 576; i += 256) W1t[i] = W1[i];
  if (t < 64) { a1s[t] = params[t]; b1s[t] = params[64 + t]; }
  // stage W2^T split into LDS (one-time): W2T[out_ch][k]
  for (int i = t; i < 4096; i += 256) {
    const int k = i >> 6, c = i & 63;
    const float x = W2[i];
    const unsigned int b = __float_as_uint(x);
    W2Thi[c][k] = (unsigned short)(b >> 16);
    const float r = x - __uint_as_float(b & 0xFFFF0000u);
    W2Tlo[c][k] = (unsigned short)(__float_as_uint(r) >> 16);
  }

  const int lane = t & 63;
  const int wv = t >> 6;
  const float sg0 = (g2[lane & 31] >= 0.0f) ? 1.0f : -1.0f;        // tile0 ch
  const float sg1 = (g2[32 + (lane & 31)] >= 0.0f) ? 1.0f : -1.0f; // tile1 ch
  __syncthreads();

  const int p_loc = t >> 1;             // phase-A point 0..127 (wave wv owns pillar wv)
  const int ch_half = (t & 1) * 32;
  const int swW = (p_loc & 7) << 3;         // phase-A write swizzle (u16 units)
  const int arow = 32 * wv + (lane & 31);   // A-frag h1 row
  const int swA = (arow & 7) << 3;          // phase-B read swizzle
  const int koff = 8 * (lane >> 5);         // k base within 16-step
  const int bcol = lane & 31;               // B-frag W2T row (tile0)
  float psum = 0.0f, psq = 0.0f;

  for (int bb = blockIdx.x; bb < NBATCH; bb += SB) {
    // ---- phase A: h1 (f32) -> split bf16 hi/lo in LDS, for this wave's pillar
    const int pil = bb * 4 + (p_loc >> 5);
    const int m = p_loc & 31;
    const float4 v = vox[bb * CHUNK + p_loc];
    const int4 cc = coords[pil];
    const int np = npnts[pil];
    float z = v.z;
#pragma unroll
    for (int s = 1; s < 64; s <<= 1) z += __shfl_xor(z, s, 64);  // 32 pts x2 lanes
    const float zc = z * (1.0f / 64.0f);
    float f[9];
    make_f(v, cc, np, m, zc, f);
#pragma unroll
    for (int j = 0; j < 8; ++j) {
      const int c0 = ch_half + 4 * j;
      float y0 = 0, y1 = 0, y2 = 0, y3 = 0;
#pragma unroll
      for (int i = 0; i < 9; ++i) {
        const float4 w = *(const float4*)&W1t[i * 64 + c0];
        y0 = fmaf(f[i], w.x, y0);
        y1 = fmaf(f[i], w.y, y1);
        y2 = fmaf(f[i], w.z, y2);
        y3 = fmaf(f[i], w.w, y3);
      }
      const float4 a = *(const float4*)&a1s[c0];
      const float4 b = *(const float4*)&b1s[c0];
      float4 h;
      h.x = fmaxf(fmaf(y0, a.x, b.x), 0.0f);
      h.y = fmaxf(fmaf(y1, a.y, b.y), 0.0f);
      h.z = fmaxf(fmaf(y2, a.z, b.z), 0.0f);
      h.w = fmaxf(fmaf(y3, a.w, b.w), 0.0f);
      // trunc-split to bf16 hi/lo (exact residuals, pure bit ops)
      const unsigned int bx = __float_as_uint(h.x), by = __float_as_uint(h.y);
      const unsigned int bz = __float_as_uint(h.z), bw = __float_as_uint(h.w);
      uint2 hiw, low;
      hiw.x = (bx >> 16) | (by & 0xFFFF0000u);
      hiw.y = (bz >> 16) | (bw & 0xFFFF0000u);
      const float rx = h.x - __uint_as_float(bx & 0xFFFF0000u);
      const float ry = h.y - __uint_as_float(by & 0xFFFF0000u);
      const float rz = h.z - __uint_as_float(bz & 0xFFFF0000u);
      const float rw = h.w - __uint_as_float(bw & 0xFFFF0000u);
      low.x = (__float_as_uint(rx) >> 16) | (__float_as_uint(ry) & 0xFFFF0000u);
      low.y = (__float_as_uint(rz) >> 16) | (__float_as_uint(rw) & 0xFFFF0000u);
      *(uint2*)&h1hi[p_loc][c0 ^ swW] = hiw;
      *(uint2*)&h1lo[p_loc][c0 ^ swW] = low;
    }
    // no barrier: wave wv wrote rows 32wv..32wv+31 and reads only those
    // (within-wave DS ordering; compiler inserts lgkmcnt waits)

    // ---- phase B: y2 = h1 @ W2 via 3-term split-bf16 MFMA, 2 channel-tiles
    f32x16 acc0, acc1;
#pragma unroll
    for (int i = 0; i < 16; ++i) { acc0[i] = 0.0f; acc1[i] = 0.0f; }
#pragma unroll
    for (int ks = 0; ks < 4; ++ks) {
      const int kk = koff + 16 * ks;
      const bfrag ahi = *(const bfrag*)&h1hi[arow][kk ^ swA];
      const bfrag alo = *(const bfrag*)&h1lo[arow][kk ^ swA];
      const bfrag bhi0 = *(const bfrag*)&W2Thi[bcol][kk];
      const bfrag blo0 = *(const bfrag*)&W2Tlo[bcol][kk];
      const bfrag bhi1 = *(const bfrag*)&W2Thi[bcol + 32][kk];
      const bfrag blo1 = *(const bfrag*)&W2Tlo[bcol + 32][kk];
      acc0 = __builtin_amdgcn_mfma_f32_32x32x16_bf16(ahi, bhi0, acc0, 0, 0, 0);
      acc1 = __builtin_amdgcn_mfma_f32_32x32x16_bf16(ahi, bhi1, acc1, 0, 0, 0);
      acc0 = __builtin_amdgcn_mfma_f32_32x32x16_bf16(ahi, blo0, acc0, 0, 0, 0);
      acc1 = __builtin_amdgcn_mfma_f32_32x32x16_bf16(ahi, blo1, acc1, 0, 0, 0);
      acc0 = __builtin_amdgcn_mfma_f32_32x32x16_bf16(alo, bhi0, acc0, 0, 0, 0);
      acc1 = __builtin_amdgcn_mfma_f32_32x32x16_bf16(alo, bhi1, acc1, 0, 0, 0);
    }
    // ---- epilogue: rows=points live in 16 regs + partner lane (lane^32)
    float s0 = 0, q0 = 0, m0 = -INFINITY, s1 = 0, q1 = 0, m1 = -INFINITY;
#pragma unroll
    for (int i = 0; i < 16; ++i) {
      const float v0 = acc0[i], v1 = acc1[i];
      s0 += v0; q0 = fmaf(v0, v0, q0); m0 = fmaxf(m0, v0 * sg0);
      s1 += v1; q1 = fmaf(v1, v1, q1); m1 = fmaxf(m1, v1 * sg1);
    }
    s0 += __shfl_xor(s0, 32, 64); q0 += __shfl_xor(q0, 32, 64);
    m0 = fmaxf(m0, __shfl_xor(m0, 32, 64));
    s1 += __shfl_xor(s1, 32, 64); q1 += __shfl_xor(q1, 32, 64);
    m1 = fmaxf(m1, __shfl_xor(m1, 32, 64));
    const bool hiHalf = lane >= 32;   // lane's own channel = lane
    psum += hiHalf ? s1 : s0;
    psq += hiHalf ? q1 : q0;
    Y2SEL[(bb * 4 + wv) * 64 + lane] = hiHalf ? m1 : m0;   // coalesced
  }

  // final block reduction: alias red arrays onto h1hi (all h1 use is done;
  // barrier separates the regions' lifetimes)
  __syncthreads();
  float* redS = (float*)&h1hi[0][0];        // 256 floats
  float* redQ = redS + 256;                 // 256 floats
  redS[wv * 64 + lane] = psum;
  redQ[wv * 64 + lane] = psq;
  __syncthreads();
  if (t < 64) {
    const float s = redS[t] + redS[64 + t] + redS[128 + t] + redS[192 + t];
    const float q = redQ[t] + redQ[64 + t] + redQ[128 + t] + redQ[192 + t];
    P2[t * SB + blockIdx.x] = s;
    P2[(64 + t) * SB + blockIdx.x] = q;
  }
}

// ------------------------------------------------- finalize layer-2 BN params

__global__ void k_fin2(const double* __restrict__ T2, const float* __restrict__ g2,
                       const float* __restrict__ b2, float* __restrict__ params) {
  const int c = threadIdx.x;  // 64
  const double mean = T2[c] / (double)NPTS;
  const double var = T2[64 + c] / (double)NPTS - mean * mean;
  const double a = (double)g2[c] / sqrt(var + 0.001);
  params[128 + c] = (float)a;
  params[192 + c] = (float)((double)b2[c] - mean * a);
}

// ------------------------------------------------- K5: final output pass.

__global__ __launch_bounds__(256) void k_final(
    const float* __restrict__ params, const float* __restrict__ Y2SEL,
    float* __restrict__ out) {
  const int idx = blockIdx.x * 256 + threadIdx.x;   // NPIL*64 total
  const int c = idx & 63;
  const float a2 = params[128 + c];
  const float b2 = params[192 + c];
  const float v = Y2SEL[idx];
  const float sel = (a2 >= 0.0f) ? v : -v;
  out[idx] = fmaxf(fmaf(sel, a2, b2), 0.0f);
}

// ---------------------------------------------------------------- launch

extern "C" void kernel_launch(void* const* d_in, const int* in_sizes, int n_in,
                              void* d_out, int out_size, void* d_ws, size_t ws_size,
                              hipStream_t stream) {
  const float4* vox = (const float4*)d_in[0];
  const int4* coords = (const int4*)d_in[1];
  const int* npnts = (const int*)d_in[2];
  const float* W1 = (const float*)d_in[3];
  const float* g1 = (const float*)d_in[4];
  const float* b1 = (const float*)d_in[5];
  const float* W2 = (const float*)d_in[6];
  const float* g2 = (const float*)d_in[7];
  const float* b2 = (const float*)d_in[8];
  float* out = (float*)d_out;

  char* w = (char*)d_ws;
  size_t off = 0;
  double* T1 = (double*)(w + off); off += 512;                 // 54 doubles
  double* T2 = (double*)(w + off); off += 1024;                // 128 doubles
  float* P1 = (float*)(w + off); off += NMOM * K1_BLOCKS * 4;  // 324 KB
  float* P2 = (float*)(w + off); off += 128 * SB * 4;          // 262 KB
  float* params = (float*)(w + off); off += 256 * 4;           // 256 f32
  float* Y2SEL = (float*)(w + off); off += (size_t)NPIL * 64 * 4;  // 12.3 MB

  k_moments<<<K1_BLOCKS, 256, 0, stream>>>(vox, coords, npnts, P1);
  k_rowreduce<<<NMOM, 256, 0, stream>>>(P1, T1, K1_BLOCKS);
  k_fin1<<<1, 64, 0, stream>>>(T1, W1, g1, b1, params);
  k_stats2<<<SB, 256, 0, stream>>>(vox, coords, npnts, W1, W2, g2, params, P2, Y2SEL);
  k_rowreduce<<<128, 256, 0, stream>>>(P2, T2, SB);
  k_fin2<<<1, 64, 0, stream>>>(T2, g2, b2, params);
  k_final<<<(NPIL * 64) / 256, 256, 0, stream>>>(params, Y2SEL, out);
}

// Round 15
// 168.095 us; speedup vs baseline: 3.6639x; 3.6639x over previous
//
#include <hip/hip_runtime.h>
#include <math.h>

#define NB 4
#define NPI 12000
#define NM 32
#define NPTS (NB*NPI*NM)      // 1536000
#define NPIL (NB*NPI)         // 48000

// k_moments config
#define K1_BLOCKS 1500
#define K1_STRIDE (K1_BLOCKS*256)   // 384000
#define K1_ITERS 4                  // NPTS / K1_STRIDE
#define NMOM 54                     // 9 Sf + 45 Sff

// heavy-kernel config: 128 points (4 pillars) per batch, all-32-slots uniform
#define CHUNK 128
#define NBATCH (NPTS/CHUNK)   // 12000
#define SB 512                // 2 blocks/CU resident
#define LDB 72                // bf16 row stride: 144B = 9*16B (16B-aligned rows)

typedef __attribute__((ext_vector_type(8))) short bfrag;     // 8 bf16 = 4 VGPRs
typedef __attribute__((ext_vector_type(16))) float f32x16;   // MFMA 32x32 acc

// ---------------------------------------------------------------- helpers

__device__ __forceinline__ void make_f(float4 v, int4 cc, int np, int m, float zc, float f[9]) {
  const float cx = ((float)cc.w + 0.5f) * 0.16f + 0.0f;
  const float cy = ((float)cc.z + 0.5f) * 0.16f - 39.68f;
  f[0] = v.x; f[1] = v.y; f[2] = v.z; f[3] = v.w;
  f[4] = v.x - cx; f[5] = v.y - cy; f[6] = cx; f[7] = cy; f[8] = zc;
  const float msk = (m < np) ? 1.0f : 0.0f;
#pragma unroll
  for (int i = 0; i < 9; ++i) f[i] *= msk;
}

// ------------------------------------------------- K1: f-moments

__global__ __launch_bounds__(256) void k_moments(
    const float4* __restrict__ vox, const int4* __restrict__ coords,
    const int* __restrict__ npnts, float* __restrict__ P1) {
  const int t = blockIdx.x * 256 + threadIdx.x;
  float acc[NMOM];
#pragma unroll
  for (int v = 0; v < NMOM; ++v) acc[v] = 0.0f;

#pragma unroll
  for (int j = 0; j < K1_ITERS; ++j) {
    const int pt = t + j * K1_STRIDE;
    const int pil = pt >> 5;
    const int m = pt & 31;
    const float4 v = vox[pt];
    const int4 cc = coords[pil];
    const int np = npnts[pil];
    float z = v.z;
#pragma unroll
    for (int s = 1; s < 32; s <<= 1) z += __shfl_xor(z, s, 32);
    const float zc = z * (1.0f / 32.0f);
    float f[9];
    make_f(v, cc, np, m, zc, f);
    int vi = 0;
#pragma unroll
    for (int i = 0; i < 9; ++i) acc[vi++] += f[i];
#pragma unroll
    for (int i = 0; i < 9; ++i)
#pragma unroll
      for (int jj = i; jj < 9; ++jj) acc[vi++] += f[i] * f[jj];
  }

#pragma unroll
  for (int v = 0; v < NMOM; ++v) {
    float x = acc[v];
#pragma unroll
    for (int s = 1; s < 64; s <<= 1) x += __shfl_xor(x, s, 64);
    acc[v] = x;
  }
  __shared__ float red[4][NMOM];
  const int wave = threadIdx.x >> 6, lane = threadIdx.x & 63;
  if (lane == 0) {
#pragma unroll
    for (int v = 0; v < NMOM; ++v) red[wave][v] = acc[v];
  }
  __syncthreads();
  if (threadIdx.x < NMOM) {
    float s = red[0][threadIdx.x] + red[1][threadIdx.x] + red[2][threadIdx.x] + red[3][threadIdx.x];
    P1[threadIdx.x * K1_BLOCKS + blockIdx.x] = s;
  }
}

// ------------------------------------------------- generic row reduce (f32 -> f64)

__global__ __launch_bounds__(256) void k_rowreduce(
    const float* __restrict__ src, double* __restrict__ dst, int ncols) {
  const int row = blockIdx.x;
  const float* p = src + row * ncols;
  double sd = 0.0;
  for (int i = threadIdx.x; i < ncols; i += 256) sd += (double)p[i];
#pragma unroll
  for (int s = 1; s < 64; s <<= 1) sd += __shfl_xor(sd, s, 64);
  __shared__ double rd[4];
  const int wave = threadIdx.x >> 6, lane = threadIdx.x & 63;
  if (lane == 0) rd[wave] = sd;
  __syncthreads();
  if (threadIdx.x == 0) dst[row] = rd[0] + rd[1] + rd[2] + rd[3];
}

// ------------------------------------------------- finalize layer-1 BN params

__global__ void k_fin1(const double* __restrict__ T1, const float* __restrict__ W1,
                       const float* __restrict__ g1, const float* __restrict__ b1,
                       float* __restrict__ params) {
  const int c = threadIdx.x;  // 64
  double w[9];
#pragma unroll
  for (int i = 0; i < 9; ++i) w[i] = (double)W1[i * 64 + c];
  double mean = 0.0;
#pragma unroll
  for (int i = 0; i < 9; ++i) mean += w[i] * T1[i];
  mean /= (double)NPTS;
  double e2 = 0.0;
  int v = 9;
#pragma unroll
  for (int i = 0; i < 9; ++i)
#pragma unroll
    for (int j = i; j < 9; ++j) {
      const double t = T1[v++] * w[i] * w[j];
      e2 += (i == j) ? t : 2.0 * t;
    }
  e2 /= (double)NPTS;
  const double var = e2 - mean * mean;
  const double a = (double)g1[c] / sqrt(var + 0.001);
  params[c] = (float)a;
  params[64 + c] = (float)((double)b1[c] - mean * a);
}

// ------------------------------------------------- K3: layer-2 via MFMA
// EXACT round-13 structure (MFMA phase B, split-bf16, uniform all-32-slots,
// no barriers in main loop; VGPR 196, 2 waves/SIMD -- R14 proved any cap
// below that collapses into spill). Round 15 single change: software
// prefetch of next iteration's vox/coords/npnts issued right after the
// current values are consumed -- hides the ~300-900cy dependent load at
// each iteration head under phase A+B compute (the R13 counters showed all
// pipes <50%: stall-bound, not throughput-bound).

__global__ __launch_bounds__(256) void k_stats2(
    const float4* __restrict__ vox, const int4* __restrict__ coords,
    const int* __restrict__ npnts, const float* __restrict__ W1,
    const float* __restrict__ W2, const float* __restrict__ g2,
    const float* __restrict__ params, float* __restrict__ P2,
    float* __restrict__ Y2SEL) {
  __shared__ __align__(16) float W1t[9 * 64];
  __shared__ __align__(16) float a1s[64], b1s[64];
  __shared__ __align__(16) unsigned short h1hi[128][LDB];   // 18432 B
  __shared__ __align__(16) unsigned short h1lo[128][LDB];   // 18432 B
  __shared__ __align__(16) unsigned short W2Thi[64][LDB];   //  9216 B
  __shared__ __align__(16) unsigned short W2Tlo[64][LDB];   //  9216 B
  __shared__ float redS[4][64], redQ[4][64];

  const int t = threadIdx.x;
  for (int i = t; i < 576; i += 256) W1t[i] = W1[i];
  if (t < 64) { a1s[t] = params[t]; b1s[t] = params[64 + t]; }
  // stage W2^T split into LDS (one-time): W2T[out_ch][k]
  for (int i = t; i < 4096; i += 256) {
    const int k = i >> 6, c = i & 63;
    const float x = W2[i];
    const unsigned int b = __float_as_uint(x);
    W2Thi[c][k] = (unsigned short)(b >> 16);
    const float r = x - __uint_as_float(b & 0xFFFF0000u);
    W2Tlo[c][k] = (unsigned short)(__float_as_uint(r) >> 16);
  }

  const int lane = t & 63;
  const int wv = t >> 6;
  const float sg0 = (g2[lane & 31] >= 0.0f) ? 1.0f : -1.0f;        // tile0 ch
  const float sg1 = (g2[32 + (lane & 31)] >= 0.0f) ? 1.0f : -1.0f; // tile1 ch
  __syncthreads();

  const int p_loc = t >> 1;             // phase-A point 0..127 (wave wv owns pillar wv)
  const int ch_half = (t & 1) * 32;
  const int arow = 32 * wv + (lane & 31);   // A-frag h1 row
  const int koff = 8 * (lane >> 5);         // k base within 16-step
  const int bcol = lane & 31;               // B-frag W2T row (tile0)
  float psum = 0.0f, psq = 0.0f;

  // ---- prefetched head values for the first iteration
  int bb0 = blockIdx.x;
  float4 v = vox[bb0 * CHUNK + p_loc];
  int4 cc = coords[bb0 * 4 + (p_loc >> 5)];
  int np = npnts[bb0 * 4 + (p_loc >> 5)];

  for (int bb = bb0; bb < NBATCH; bb += SB) {
    // ---- phase A: h1 (f32) -> split bf16 hi/lo in LDS, for this wave's pillar
    const int m = p_loc & 31;
    float z = v.z;
#pragma unroll
    for (int s = 1; s < 64; s <<= 1) z += __shfl_xor(z, s, 64);  // 32 pts x2 lanes
    const float zc = z * (1.0f / 64.0f);
    float f[9];
    make_f(v, cc, np, m, zc, f);

    // ---- prefetch NEXT iteration's inputs (current v/cc/np consumed above);
    // clamped address keeps the final iteration's loads in-bounds.
    const int bbn = bb + SB;
    const int bbs = (bbn < NBATCH) ? bbn : bb;
    v = vox[bbs * CHUNK + p_loc];
    cc = coords[bbs * 4 + (p_loc >> 5)];
    np = npnts[bbs * 4 + (p_loc >> 5)];

#pragma unroll
    for (int j = 0; j < 8; ++j) {
      const int c0 = ch_half + 4 * j;
      float y0 = 0, y1 = 0, y2 = 0, y3 = 0;
#pragma unroll
      for (int i = 0; i < 9; ++i) {
        const float4 w = *(const float4*)&W1t[i * 64 + c0];
        y0 = fmaf(f[i], w.x, y0);
        y1 = fmaf(f[i], w.y, y1);
        y2 = fmaf(f[i], w.z, y2);
        y3 = fmaf(f[i], w.w, y3);
      }
      const float4 a = *(const float4*)&a1s[c0];
      const float4 b = *(const float4*)&b1s[c0];
      float4 h;
      h.x = fmaxf(fmaf(y0, a.x, b.x), 0.0f);
      h.y = fmaxf(fmaf(y1, a.y, b.y), 0.0f);
      h.z = fmaxf(fmaf(y2, a.z, b.z), 0.0f);
      h.w = fmaxf(fmaf(y3, a.w, b.w), 0.0f);
      // trunc-split to bf16 hi/lo (exact residuals, pure bit ops)
      const unsigned int bx = __float_as_uint(h.x), by = __float_as_uint(h.y);
      const unsigned int bz = __float_as_uint(h.z), bw = __float_as_uint(h.w);
      uint2 hiw, low;
      hiw.x = (bx >> 16) | (by & 0xFFFF0000u);
      hiw.y = (bz >> 16) | (bw & 0xFFFF0000u);
      const float rx = h.x - __uint_as_float(bx & 0xFFFF0000u);
      const float ry = h.y - __uint_as_float(by & 0xFFFF0000u);
      const float rz = h.z - __uint_as_float(bz & 0xFFFF0000u);
      const float rw = h.w - __uint_as_float(bw & 0xFFFF0000u);
      low.x = (__float_as_uint(rx) >> 16) | (__float_as_uint(ry) & 0xFFFF0000u);
      low.y = (__float_as_uint(rz) >> 16) | (__float_as_uint(rw) & 0xFFFF0000u);
      *(uint2*)&h1hi[p_loc][c0] = hiw;
      *(uint2*)&h1lo[p_loc][c0] = low;
    }
    // no barrier: wave wv wrote rows 32wv..32wv+31 and reads only those
    // (within-wave DS ordering; compiler inserts lgkmcnt waits)

    // ---- phase B: y2 = h1 @ W2 via 3-term split-bf16 MFMA, 2 channel-tiles
    f32x16 acc0, acc1;
#pragma unroll
    for (int i = 0; i < 16; ++i) { acc0[i] = 0.0f; acc1[i] = 0.0f; }
#pragma unroll
    for (int ks = 0; ks < 4; ++ks) {
      const int kk = koff + 16 * ks;
      const bfrag ahi = *(const bfrag*)&h1hi[arow][kk];
      const bfrag alo = *(const bfrag*)&h1lo[arow][kk];
      const bfrag bhi0 = *(const bfrag*)&W2Thi[bcol][kk];
      const bfrag blo0 = *(const bfrag*)&W2Tlo[bcol][kk];
      const bfrag bhi1 = *(const bfrag*)&W2Thi[bcol + 32][kk];
      const bfrag blo1 = *(const bfrag*)&W2Tlo[bcol + 32][kk];
      acc0 = __builtin_amdgcn_mfma_f32_32x32x16_bf16(ahi, bhi0, acc0, 0, 0, 0);
      acc1 = __builtin_amdgcn_mfma_f32_32x32x16_bf16(ahi, bhi1, acc1, 0, 0, 0);
      acc0 = __builtin_amdgcn_mfma_f32_32x32x16_bf16(ahi, blo0, acc0, 0, 0, 0);
      acc1 = __builtin_amdgcn_mfma_f32_32x32x16_bf16(ahi, blo1, acc1, 0, 0, 0);
      acc0 = __builtin_amdgcn_mfma_f32_32x32x16_bf16(alo, bhi0, acc0, 0, 0, 0);
      acc1 = __builtin_amdgcn_mfma_f32_32x32x16_bf16(alo, bhi1, acc1, 0, 0, 0);
    }
    // ---- epilogue: rows=points live in 16 regs + partner lane (lane^32)
    float s0 = 0, q0 = 0, m0 = -INFINITY, s1 = 0, q1 = 0, m1 = -INFINITY;
#pragma unroll
    for (int i = 0; i < 16; ++i) {
      const float v0 = acc0[i], v1 = acc1[i];
      s0 += v0; q0 = fmaf(v0, v0, q0); m0 = fmaxf(m0, v0 * sg0);
      s1 += v1; q1 = fmaf(v1, v1, q1); m1 = fmaxf(m1, v1 * sg1);
    }
    s0 += __shfl_xor(s0, 32, 64); q0 += __shfl_xor(q0, 32, 64);
    m0 = fmaxf(m0, __shfl_xor(m0, 32, 64));
    s1 += __shfl_xor(s1, 32, 64); q1 += __shfl_xor(q1, 32, 64);
    m1 = fmaxf(m1, __shfl_xor(m1, 32, 64));
    const bool hiHalf = lane >= 32;   // lane's own channel = lane
    psum += hiHalf ? s1 : s0;
    psq += hiHalf ? q1 : q0;
    Y2SEL[(bb * 4 + wv) * 64 + lane] = hiHalf ? m1 : m0;   // coalesced
  }

  redS[wv][lane] = psum;
  redQ[wv][lane] = psq;
  __syncthreads();
  if (t < 64) {
    const float s = redS[0][t] + redS[1][t] + redS[2][t] + redS[3][t];
    const float q = redQ[0][t] + redQ[1][t] + redQ[2][t] + redQ[3][t];
    P2[t * SB + blockIdx.x] = s;
    P2[(64 + t) * SB + blockIdx.x] = q;
  }
}

// ------------------------------------------------- finalize layer-2 BN params

__global__ void k_fin2(const double* __restrict__ T2, const float* __restrict__ g2,
                       const float* __restrict__ b2, float* __restrict__ params) {
  const int c = threadIdx.x;  // 64
  const double mean = T2[c] / (double)NPTS;
  const double var = T2[64 + c] / (double)NPTS - mean * mean;
  const double a = (double)g2[c] / sqrt(var + 0.001);
  params[128 + c] = (float)a;
  params[192 + c] = (float)((double)b2[c] - mean * a);
}

// ------------------------------------------------- K5: final output pass.

__global__ __launch_bounds__(256) void k_final(
    const float* __restrict__ params, const float* __restrict__ Y2SEL,
    float* __restrict__ out) {
  const int idx = blockIdx.x * 256 + threadIdx.x;   // NPIL*64 total
  const int c = idx & 63;
  const float a2 = params[128 + c];
  const float b2 = params[192 + c];
  const float v = Y2SEL[idx];
  const float sel = (a2 >= 0.0f) ? v : -v;
  out[idx] = fmaxf(fmaf(sel, a2, b2), 0.0f);
}

// ---------------------------------------------------------------- launch

extern "C" void kernel_launch(void* const* d_in, const int* in_sizes, int n_in,
                              void* d_out, int out_size, void* d_ws, size_t ws_size,
                              hipStream_t stream) {
  const float4* vox = (const float4*)d_in[0];
  const int4* coords = (const int4*)d_in[1];
  const int* npnts = (const int*)d_in[2];
  const float* W1 = (const float*)d_in[3];
  const float* g1 = (const float*)d_in[4];
  const float* b1 = (const float*)d_in[5];
  const float* W2 = (const float*)d_in[6];
  const float* g2 = (const float*)d_in[7];
  const float* b2 = (const float*)d_in[8];
  float* out = (float*)d_out;

  char* w = (char*)d_ws;
  size_t off = 0;
  double* T1 = (double*)(w + off); off += 512;                 // 54 doubles
  double* T2 = (double*)(w + off); off += 1024;                // 128 doubles
  float* P1 = (float*)(w + off); off += NMOM * K1_BLOCKS * 4;  // 324 KB
  float* P2 = (float*)(w + off); off += 128 * SB * 4;          // 262 KB
  float* params = (float*)(w + off); off += 256 * 4;           // 256 f32
  float* Y2SEL = (float*)(w + off); off += (size_t)NPIL * 64 * 4;  // 12.3 MB

  k_moments<<<K1_BLOCKS, 256, 0, stream>>>(vox, coords, npnts, P1);
  k_rowreduce<<<NMOM, 256, 0, stream>>>(P1, T1, K1_BLOCKS);
  k_fin1<<<1, 64, 0, stream>>>(T1, W1, g1, b1, params);
  k_stats2<<<SB, 256, 0, stream>>>(vox, coords, npnts, W1, W2, g2, params, P2, Y2SEL);
  k_rowreduce<<<128, 256, 0, stream>>>(P2, T2, SB);
  k_fin2<<<1, 64, 0, stream>>>(T2, g2, b2, params);
  k_final<<<(NPIL * 64) / 256, 256, 0, stream>>>(params, Y2SEL, out);
}

// Round 16
// 115.833 us; speedup vs baseline: 5.3170x; 1.4512x over previous
//
#include <hip/hip_runtime.h>
#include <math.h>

#define NB 4
#define NPI 12000
#define NM 32
#define NPTS (NB*NPI*NM)      // 1536000
#define NPIL (NB*NPI)         // 48000

// k_moments config
#define K1_BLOCKS 1500
#define K1_STRIDE (K1_BLOCKS*256)   // 384000
#define K1_ITERS 4                  // NPTS / K1_STRIDE
#define NMOM 54                     // 9 Sf + 45 Sff

// heavy-kernel config
#define CHUNK 128
#define NBATCH (NPTS/CHUNK)   // 12000
#define SB 512                // 2 blocks/CU resident

typedef __attribute__((ext_vector_type(8))) short bfrag;     // 8 bf16 = 4 VGPRs
typedef __attribute__((ext_vector_type(16))) float f32x16;   // MFMA 32x32 acc

// ---------------------------------------------------------------- helpers

__device__ __forceinline__ void make_f(float4 v, int4 cc, int np, int m, float zc, float f[9]) {
  const float cx = ((float)cc.w + 0.5f) * 0.16f + 0.0f;
  const float cy = ((float)cc.z + 0.5f) * 0.16f - 39.68f;
  f[0] = v.x; f[1] = v.y; f[2] = v.z; f[3] = v.w;
  f[4] = v.x - cx; f[5] = v.y - cy; f[6] = cx; f[7] = cy; f[8] = zc;
  const float msk = (m < np) ? 1.0f : 0.0f;
#pragma unroll
  for (int i = 0; i < 9; ++i) f[i] *= msk;
}

// ------------------------------------------------- K1: f-moments

__global__ __launch_bounds__(256) void k_moments(
    const float4* __restrict__ vox, const int4* __restrict__ coords,
    const int* __restrict__ npnts, float* __restrict__ P1) {
  const int t = blockIdx.x * 256 + threadIdx.x;
  float acc[NMOM];
#pragma unroll
  for (int v = 0; v < NMOM; ++v) acc[v] = 0.0f;

#pragma unroll
  for (int j = 0; j < K1_ITERS; ++j) {
    const int pt = t + j * K1_STRIDE;
    const int pil = pt >> 5;
    const int m = pt & 31;
    const float4 v = vox[pt];
    const int4 cc = coords[pil];
    const int np = npnts[pil];
    float z = v.z;
#pragma unroll
    for (int s = 1; s < 32; s <<= 1) z += __shfl_xor(z, s, 32);
    const float zc = z * (1.0f / 32.0f);
    float f[9];
    make_f(v, cc, np, m, zc, f);
    int vi = 0;
#pragma unroll
    for (int i = 0; i < 9; ++i) acc[vi++] += f[i];
#pragma unroll
    for (int i = 0; i < 9; ++i)
#pragma unroll
      for (int jj = i; jj < 9; ++jj) acc[vi++] += f[i] * f[jj];
  }

#pragma unroll
  for (int v = 0; v < NMOM; ++v) {
    float x = acc[v];
#pragma unroll
    for (int s = 1; s < 64; s <<= 1) x += __shfl_xor(x, s, 64);
    acc[v] = x;
  }
  __shared__ float red[4][NMOM];
  const int wave = threadIdx.x >> 6, lane = threadIdx.x & 63;
  if (lane == 0) {
#pragma unroll
    for (int v = 0; v < NMOM; ++v) red[wave][v] = acc[v];
  }
  __syncthreads();
  if (threadIdx.x < NMOM) {
    float s = red[0][threadIdx.x] + red[1][threadIdx.x] + red[2][threadIdx.x] + red[3][threadIdx.x];
    P1[threadIdx.x * K1_BLOCKS + blockIdx.x] = s;
  }
}

// ------------------------------------------------- generic row reduce (f32 -> f64)

__global__ __launch_bounds__(256) void k_rowreduce(
    const float* __restrict__ src, double* __restrict__ dst, int ncols) {
  const int row = blockIdx.x;
  const float* p = src + row * ncols;
  double sd = 0.0;
  for (int i = threadIdx.x; i < ncols; i += 256) sd += (double)p[i];
#pragma unroll
  for (int s = 1; s < 64; s <<= 1) sd += __shfl_xor(sd, s, 64);
  __shared__ double rd[4];
  const int wave = threadIdx.x >> 6, lane = threadIdx.x & 63;
  if (lane == 0) rd[wave] = sd;
  __syncthreads();
  if (threadIdx.x == 0) dst[row] = rd[0] + rd[1] + rd[2] + rd[3];
}

// ------------------------------------------------- finalize layer-1 BN params

__global__ void k_fin1(const double* __restrict__ T1, const float* __restrict__ W1,
                       const float* __restrict__ g1, const float* __restrict__ b1,
                       float* __restrict__ params) {
  const int c = threadIdx.x;  // 64
  double w[9];
#pragma unroll
  for (int i = 0; i < 9; ++i) w[i] = (double)W1[i * 64 + c];
  double mean = 0.0;
#pragma unroll
  for (int i = 0; i < 9; ++i) mean += w[i] * T1[i];
  mean /= (double)NPTS;
  double e2 = 0.0;
  int v = 9;
#pragma unroll
  for (int i = 0; i < 9; ++i)
#pragma unroll
    for (int j = i; j < 9; ++j) {
      const double t = T1[v++] * w[i] * w[j];
      e2 += (i == j) ? t : 2.0 * t;
    }
  e2 /= (double)NPTS;
  const double var = e2 - mean * mean;
  const double a = (double)g1[c] / sqrt(var + 0.001);
  params[c] = (float)a;
  params[64 + c] = (float)((double)b1[c] - mean * a);
}

// ------------------------------------------------- K3: both layers via MFMA
// R15 post-mortem: kernel was DS-pipe-bound -- phase A's broadcast W1 reads
// were ~1050cy of the measured ~2000cy DS per wave-iteration. Fix: phase A is
// also a GEMM (32pts x K=9pad16) @ (16 x 64ch) -> one 32x32x16 k-step, 3-term
// split-bf16 like phase B (operand conventions verified by R13's correctness).
// DS now: f-write 2 b128 + f-frag 2 + W1T frags (hoisted, invariant) + 64
// scalar b16 h1 writebacks + phase B 24 b128 + shuffles ~= 1100cy/wave-iter.
// h1/W2T in [.][64] with XOR swizzle col^=(row&7)<<3 (both sides). LDS=64000B.

__global__ __launch_bounds__(256) void k_stats2(
    const float4* __restrict__ vox, const int4* __restrict__ coords,
    const int* __restrict__ npnts, const float* __restrict__ W1,
    const float* __restrict__ W2, const float* __restrict__ g2,
    const float* __restrict__ params, float* __restrict__ P2,
    float* __restrict__ Y2SEL) {
  __shared__ __align__(16) unsigned short W1Thi[64][16];   // 2048 B
  __shared__ __align__(16) unsigned short W1Tlo[64][16];   // 2048 B
  __shared__ __align__(16) float a1s[64], b1s[64];         //  512 B
  __shared__ __align__(16) unsigned short fhi[128][16];    // 4096 B (1-bit swz)
  __shared__ __align__(16) unsigned short flo[128][16];    // 4096 B
  __shared__ __align__(16) unsigned short h1hi[128][64];   // 16384 B (swz)
  __shared__ __align__(16) unsigned short h1lo[128][64];   // 16384 B (swz)
  __shared__ __align__(16) unsigned short W2Thi[64][64];   //  8192 B (swz)
  __shared__ __align__(16) unsigned short W2Tlo[64][64];   //  8192 B (swz)
  __shared__ float redS[4][64], redQ[4][64];               //  2048 B
  // total 64000 B <= 65536

  const int t = threadIdx.x;
  if (t < 64) { a1s[t] = params[t]; b1s[t] = params[64 + t]; }
  // stage W1^T split (k padded 9->16): W1T[ch][k]
  for (int i = t; i < 1024; i += 256) {
    const int c = i >> 4, k = i & 15;
    const float x = (k < 9) ? W1[k * 64 + c] : 0.0f;
    const unsigned int b = __float_as_uint(x);
    W1Thi[c][k] = (unsigned short)(b >> 16);
    const float r = x - __uint_as_float(b & 0xFFFF0000u);
    W1Tlo[c][k] = (unsigned short)(__float_as_uint(r) >> 16);
  }
  // stage W2^T split, swizzled: element (ch,k) at col k ^ ((ch&7)<<3)
  for (int i = t; i < 4096; i += 256) {
    const int k = i >> 6, c = i & 63;
    const float x = W2[i];
    const unsigned int b = __float_as_uint(x);
    const float r = x - __uint_as_float(b & 0xFFFF0000u);
    const int kc = k ^ ((c & 7) << 3);
    W2Thi[c][kc] = (unsigned short)(b >> 16);
    W2Tlo[c][kc] = (unsigned short)(__float_as_uint(r) >> 16);
  }

  const int lane = t & 63;
  const int wv = t >> 6;                      // wave owns pillar wv of each batch
  const int ch = lane & 31;                   // tile-local channel
  const float sg0 = (g2[ch] >= 0.0f) ? 1.0f : -1.0f;
  const float sg1 = (g2[32 + ch] >= 0.0f) ? 1.0f : -1.0f;
  __syncthreads();

  const int arow = 32 * wv + ch;              // A row = point (frag row = lane&31)
  const int koff = 8 * (lane >> 5);           // k base within 16-wide step
  const int swf = (arow & 1) << 3;            // f-array swizzle
  const int swB = (ch & 7) << 3;              // W2T read swizzle (bcol=ch)
  // hoist loop-invariant BN1 scalars + W1T fragments into registers
  const float a10 = a1s[ch], b10 = b1s[ch];
  const float a11 = a1s[32 + ch], b11 = b1s[32 + ch];
  const bfrag w1h0 = *(const bfrag*)&W1Thi[ch][koff];
  const bfrag w1l0 = *(const bfrag*)&W1Tlo[ch][koff];
  const bfrag w1h1 = *(const bfrag*)&W1Thi[32 + ch][koff];
  const bfrag w1l1 = *(const bfrag*)&W1Tlo[32 + ch][koff];

  float psum = 0.0f, psq = 0.0f;

  // prefetched inputs (this wave's pillar only; 2 lanes dup per point)
  int bb0 = blockIdx.x;
  float4 v = vox[bb0 * CHUNK + 32 * wv + ch];
  int4 cc = coords[bb0 * 4 + wv];
  int np = npnts[bb0 * 4 + wv];

  for (int bb = bb0; bb < NBATCH; bb += SB) {
    // ---- f for this pillar (each lane: point ch=lane&31; halves dup)
    float z = v.z;
#pragma unroll
    for (int s = 1; s < 64; s <<= 1) z += __shfl_xor(z, s, 64);  // 2x sum
    const float zc = z * (1.0f / 64.0f);
    float f[9];
    make_f(v, cc, np, ch, zc, f);

    // ---- prefetch next iteration's inputs (consumed above)
    {
      const int bbn = bb + SB;
      const int bbs = (bbn < NBATCH) ? bbn : bb;
      v = vox[bbs * CHUNK + 32 * wv + ch];
      cc = coords[bbs * 4 + wv];
      np = npnts[bbs * 4 + wv];
    }

    // ---- pack f -> bf16 part (lane<32: hi, lane>=32: lo), write 32B row
    {
      unsigned int pk[8];
#pragma unroll
      for (int i = 0; i < 8; ++i) pk[i] = 0u;
#pragma unroll
      for (int i = 0; i < 9; ++i) {
        const unsigned int b = __float_as_uint(f[i]);
        const float r = f[i] - __uint_as_float(b & 0xFFFF0000u);
        const unsigned int hi = b >> 16;
        const unsigned int lo = __float_as_uint(r) >> 16;
        const unsigned int part = (lane < 32) ? hi : lo;
        pk[i >> 1] |= part << ((i & 1) * 16);
      }
      unsigned short* dst = (lane < 32) ? &fhi[arow][0] : &flo[arow][0];
      uint4 q0; q0.x = pk[0]; q0.y = pk[1]; q0.z = pk[2]; q0.w = pk[3];
      uint4 q1; q1.x = pk[4]; q1.y = pk[5]; q1.z = pk[6]; q1.w = pk[7];
      *(uint4*)(dst + (0 ^ swf)) = q0;
      *(uint4*)(dst + (8 ^ swf)) = q1;
    }

    // ---- phase A: y1 = f @ W1 (one k-step, 3 split terms, 2 channel tiles)
    f32x16 yA0, yA1;
#pragma unroll
    for (int i = 0; i < 16; ++i) { yA0[i] = 0.0f; yA1[i] = 0.0f; }
    {
      const bfrag fa_hi = *(const bfrag*)&fhi[arow][koff ^ swf];
      const bfrag fa_lo = *(const bfrag*)&flo[arow][koff ^ swf];
      yA0 = __builtin_amdgcn_mfma_f32_32x32x16_bf16(fa_hi, w1h0, yA0, 0, 0, 0);
      yA1 = __builtin_amdgcn_mfma_f32_32x32x16_bf16(fa_hi, w1h1, yA1, 0, 0, 0);
      yA0 = __builtin_amdgcn_mfma_f32_32x32x16_bf16(fa_hi, w1l0, yA0, 0, 0, 0);
      yA1 = __builtin_amdgcn_mfma_f32_32x32x16_bf16(fa_hi, w1l1, yA1, 0, 0, 0);
      yA0 = __builtin_amdgcn_mfma_f32_32x32x16_bf16(fa_lo, w1h0, yA0, 0, 0, 0);
      yA1 = __builtin_amdgcn_mfma_f32_32x32x16_bf16(fa_lo, w1h1, yA1, 0, 0, 0);
    }

    // ---- BN1 + relu + split-write h1 (C layout: col=ch, row=(reg&3)+8*(reg>>2)+4*(lane>>5))
    const int rbase = 4 * (lane >> 5);
#pragma unroll
    for (int reg = 0; reg < 16; ++reg) {
      const int pt = (reg & 3) + 8 * (reg >> 2) + rbase;
      const int row = 32 * wv + pt;
      const int swz = (pt & 7) << 3;
      {
        const float h = fmaxf(fmaf(yA0[reg], a10, b10), 0.0f);
        const unsigned int b = __float_as_uint(h);
        const float r = h - __uint_as_float(b & 0xFFFF0000u);
        h1hi[row][ch ^ swz] = (unsigned short)(b >> 16);
        h1lo[row][ch ^ swz] = (unsigned short)(__float_as_uint(r) >> 16);
      }
      {
        const float h = fmaxf(fmaf(yA1[reg], a11, b11), 0.0f);
        const unsigned int b = __float_as_uint(h);
        const float r = h - __uint_as_float(b & 0xFFFF0000u);
        h1hi[row][(32 + ch) ^ swz] = (unsigned short)(b >> 16);
        h1lo[row][(32 + ch) ^ swz] = (unsigned short)(__float_as_uint(r) >> 16);
      }
    }
    // no barrier: wave wrote rows 32wv..32wv+31 and reads only those
    // (within-wave DS ordering)

    // ---- phase B: y2 = h1 @ W2 (4 k-steps, 3 split terms, 2 channel tiles)
    f32x16 acc0, acc1;
#pragma unroll
    for (int i = 0; i < 16; ++i) { acc0[i] = 0.0f; acc1[i] = 0.0f; }
    const int swA = (arow & 7) << 3;
#pragma unroll
    for (int ks = 0; ks < 4; ++ks) {
      const int kk = koff + 16 * ks;
      const bfrag ahi = *(const bfrag*)&h1hi[arow][kk ^ swA];
      const bfrag alo = *(const bfrag*)&h1lo[arow][kk ^ swA];
      const bfrag bhi0 = *(const bfrag*)&W2Thi[ch][kk ^ swB];
      const bfrag blo0 = *(const bfrag*)&W2Tlo[ch][kk ^ swB];
      const bfrag bhi1 = *(const bfrag*)&W2Thi[32 + ch][kk ^ swB];
      const bfrag blo1 = *(const bfrag*)&W2Tlo[32 + ch][kk ^ swB];
      acc0 = __builtin_amdgcn_mfma_f32_32x32x16_bf16(ahi, bhi0, acc0, 0, 0, 0);
      acc1 = __builtin_amdgcn_mfma_f32_32x32x16_bf16(ahi, bhi1, acc1, 0, 0, 0);
      acc0 = __builtin_amdgcn_mfma_f32_32x32x16_bf16(ahi, blo0, acc0, 0, 0, 0);
      acc1 = __builtin_amdgcn_mfma_f32_32x32x16_bf16(ahi, blo1, acc1, 0, 0, 0);
      acc0 = __builtin_amdgcn_mfma_f32_32x32x16_bf16(alo, bhi0, acc0, 0, 0, 0);
      acc1 = __builtin_amdgcn_mfma_f32_32x32x16_bf16(alo, bhi1, acc1, 0, 0, 0);
    }

    // ---- epilogue: rows=points in 16 regs + partner lane (lane^32)
    float s0 = 0, q0 = 0, m0 = -INFINITY, s1 = 0, q1 = 0, m1 = -INFINITY;
#pragma unroll
    for (int i = 0; i < 16; ++i) {
      const float v0 = acc0[i], v1 = acc1[i];
      s0 += v0; q0 = fmaf(v0, v0, q0); m0 = fmaxf(m0, v0 * sg0);
      s1 += v1; q1 = fmaf(v1, v1, q1); m1 = fmaxf(m1, v1 * sg1);
    }
    s0 += __shfl_xor(s0, 32, 64); q0 += __shfl_xor(q0, 32, 64);
    m0 = fmaxf(m0, __shfl_xor(m0, 32, 64));
    s1 += __shfl_xor(s1, 32, 64); q1 += __shfl_xor(q1, 32, 64);
    m1 = fmaxf(m1, __shfl_xor(m1, 32, 64));
    const bool hiHalf = lane >= 32;   // lane's own channel = lane
    psum += hiHalf ? s1 : s0;
    psq += hiHalf ? q1 : q0;
    Y2SEL[(bb * 4 + wv) * 64 + lane] = hiHalf ? m1 : m0;   // coalesced
  }

  redS[wv][lane] = psum;
  redQ[wv][lane] = psq;
  __syncthreads();
  if (t < 64) {
    const float s = redS[0][t] + redS[1][t] + redS[2][t] + redS[3][t];
    const float q = redQ[0][t] + redQ[1][t] + redQ[2][t] + redQ[3][t];
    P2[t * SB + blockIdx.x] = s;
    P2[(64 + t) * SB + blockIdx.x] = q;
  }
}

// ------------------------------------------------- finalize layer-2 BN params

__global__ void k_fin2(const double* __restrict__ T2, const float* __restrict__ g2,
                       const float* __restrict__ b2, float* __restrict__ params) {
  const int c = threadIdx.x;  // 64
  const double mean = T2[c] / (double)NPTS;
  const double var = T2[64 + c] / (double)NPTS - mean * mean;
  const double a = (double)g2[c] / sqrt(var + 0.001);
  params[128 + c] = (float)a;
  params[192 + c] = (float)((double)b2[c] - mean * a);
}

// ------------------------------------------------- K5: final output pass.

__global__ __launch_bounds__(256) void k_final(
    const float* __restrict__ params, const float* __restrict__ Y2SEL,
    float* __restrict__ out) {
  const int idx = blockIdx.x * 256 + threadIdx.x;   // NPIL*64 total
  const int c = idx & 63;
  const float a2 = params[128 + c];
  const float b2 = params[192 + c];
  const float v = Y2SEL[idx];
  const float sel = (a2 >= 0.0f) ? v : -v;
  out[idx] = fmaxf(fmaf(sel, a2, b2), 0.0f);
}

// ---------------------------------------------------------------- launch

extern "C" void kernel_launch(void* const* d_in, const int* in_sizes, int n_in,
                              void* d_out, int out_size, void* d_ws, size_t ws_size,
                              hipStream_t stream) {
  const float4* vox = (const float4*)d_in[0];
  const int4* coords = (const int4*)d_in[1];
  const int* npnts = (const int*)d_in[2];
  const float* W1 = (const float*)d_in[3];
  const float* g1 = (const float*)d_in[4];
  const float* b1 = (const float*)d_in[5];
  const float* W2 = (const float*)d_in[6];
  const float* g2 = (const float*)d_in[7];
  const float* b2 = (const float*)d_in[8];
  float* out = (float*)d_out;

  char* w = (char*)d_ws;
  size_t off = 0;
  double* T1 = (double*)(w + off); off += 512;                 // 54 doubles
  double* T2 = (double*)(w + off); off += 1024;                // 128 doubles
  float* P1 = (float*)(w + off); off += NMOM * K1_BLOCKS * 4;  // 324 KB
  float* P2 = (float*)(w + off); off += 128 * SB * 4;          // 262 KB
  float* params = (float*)(w + off); off += 256 * 4;           // 256 f32
  float* Y2SEL = (float*)(w + off); off += (size_t)NPIL * 64 * 4;  // 12.3 MB

  k_moments<<<K1_BLOCKS, 256, 0, stream>>>(vox, coords, npnts, P1);
  k_rowreduce<<<NMOM, 256, 0, stream>>>(P1, T1, K1_BLOCKS);
  k_fin1<<<1, 64, 0, stream>>>(T1, W1, g1, b1, params);
  k_stats2<<<SB, 256, 0, stream>>>(vox, coords, npnts, W1, W2, g2, params, P2, Y2SEL);
  k_rowreduce<<<128, 256, 0, stream>>>(P2, T2, SB);
  k_fin2<<<1, 64, 0, stream>>>(T2, g2, b2, params);
  k_final<<<(NPIL * 64) / 256, 256, 0, stream>>>(params, Y2SEL, out);
}